// Round 1
// baseline (861.075 us; speedup 1.0000x reference)
//
#include <hip/hip_runtime.h>
#include <math.h>

#define L_LEN  3072
#define MSUB   1024
#define CH512  512
#define TOPK   40
#define NBATCH 8

// ---------------------------------------------------------------------------
// In-LDS 3072-point complex FFT: N = 3 x 1024.
// Input must be placed digit-reversed: x[3m+r] -> index r*1024 + bitrev10(m).
// After this routine, spectrum is in natural order.
// sgn = -1: forward (e^{-i...});  sgn = +1: inverse (unnormalized).
// Caller must have a __syncthreads() between writing re/im and calling this.
// ---------------------------------------------------------------------------
__device__ __forceinline__ void fft3072(float* re, float* im, int tid, float sgn)
{
    const float TWO_PI = 6.28318530717958647692f;
    // 10 radix-2 stages on the three independent 1024-point subarrays
    for (int s = 0; s < 10; s++) {
        int half = 1 << s;
        #pragma unroll
        for (int ii = 0; ii < 6; ii++) {
            int idx = tid + (ii << 8);          // 0..1535 : 1536 butterflies/stage
            int sub = idx >> 9;                 // which 1024-subarray
            int j   = idx & 511;                // butterfly within subarray
            int pos = j & (half - 1);
            int i0  = (sub << 10) + (((j >> s) << (s + 1)) | pos);
            int i1  = i0 + half;
            float ang = sgn * TWO_PI * (float)pos / (float)(half << 1);
            float c, sn;
            __sincosf(ang, &sn, &c);
            float br = re[i1], bi = im[i1];
            float tr = c * br - sn * bi;
            float ti = c * bi + sn * br;
            float ar = re[i0], ai = im[i0];
            re[i1] = ar - tr; im[i1] = ai - ti;
            re[i0] = ar + tr; im[i0] = ai + ti;
        }
        __syncthreads();
    }
    // radix-3 combine: X[k + 1024*j] = Y0[k] + w^j*(W1*Y1[k]) + w^{2j}*(W2*Y2[k])
    #pragma unroll
    for (int ii = 0; ii < 4; ii++) {
        int kk = tid + (ii << 8);               // 0..1023
        float ang1 = sgn * TWO_PI * (float)kk / 3072.0f;
        float c1, s1;
        __sincosf(ang1, &s1, &c1);
        float c2 = c1 * c1 - s1 * s1;           // W2 = W1^2
        float s2 = 2.0f * c1 * s1;
        float y0r = re[kk],        y0i = im[kk];
        float y1r = re[1024 + kk], y1i = im[1024 + kk];
        float y2r = re[2048 + kk], y2i = im[2048 + kk];
        float t1r = c1 * y1r - s1 * y1i, t1i = c1 * y1i + s1 * y1r;
        float t2r = c2 * y2r - s2 * y2i, t2i = c2 * y2i + s2 * y2r;
        float ur = t1r + t2r, ui = t1i + t2i;
        float vr = t1r - t2r, vi = t1i - t2i;
        float mr = y0r - 0.5f * ur, mi = y0i - 0.5f * ui;
        float s3 = sgn * 0.86602540378443864676f;
        re[kk]        = y0r + ur;       im[kk]        = y0i + ui;
        re[1024 + kk] = mr - s3 * vi;   im[1024 + kk] = mi + s3 * vr;
        re[2048 + kk] = mr + s3 * vi;   im[2048 + kk] = mi - s3 * vr;
    }
    __syncthreads();
}

// ---------------------------------------------------------------------------
// Kernel A: per (b, h, e-group of 8): packed FFT z = q + i*k, extract
// P[f] = Q[f]*conj(K[f]) via Hermitian split, accumulate over 8 channels in
// LDS, then atomically add into the per-batch spectrum sum S[b].
// Grid: 512 blocks = B(8) * H(8) * egroups(8). 256 threads.
// ---------------------------------------------------------------------------
__global__ __launch_bounds__(256) void corr_fft_kernel(
    const float* __restrict__ q, const float* __restrict__ k,
    float* __restrict__ S_re, float* __restrict__ S_im)
{
    __shared__ float re[L_LEN], im[L_LEN], aR[L_LEN], aI[L_LEN];
    int blk = blockIdx.x;
    int b   = blk >> 6;          // /64
    int rem = blk & 63;
    int h   = rem >> 3;
    int eg  = rem & 7;
    int tid = threadIdx.x;

    for (int i = tid; i < L_LEN; i += 256) { aR[i] = 0.0f; aI[i] = 0.0f; }

    size_t base_bh = (size_t)b * L_LEN * CH512 + (size_t)h * 64;

    for (int ec = 0; ec < 8; ec++) {
        int e = (eg << 3) + ec;
        const float* qp = q + base_bh + e;
        const float* kp = k + base_bh + e;
        __syncthreads();   // previous channel's readers of re/im are done (also covers aR init)
        #pragma unroll
        for (int it = 0; it < 12; it++) {
            int n = tid + (it << 8);
            int m = n / 3;
            int r = n - 3 * m;
            int dst = (r << 10) + (__brev((unsigned)m) >> 22);
            re[dst] = qp[(size_t)n * CH512];
            im[dst] = kp[(size_t)n * CH512];
        }
        __syncthreads();
        fft3072(re, im, tid, -1.0f);
        // P = (i/4) * (A+B) * conj(A-B),  A = Z[f], B = conj(Z[(N-f)%N])
        #pragma unroll
        for (int it = 0; it < 12; it++) {
            int f = tid + (it << 8);
            int g = (f == 0) ? 0 : (L_LEN - f);
            float ar = re[f], ai = im[f];
            float br = re[g], bi = -im[g];
            float ur = ar + br, ui = ai + bi;
            float vr = ar - br, vi = ai - bi;
            aR[f] += 0.25f * (ur * vi - ui * vr);
            aI[f] += 0.25f * (ur * vr + ui * vi);
        }
    }
    __syncthreads();
    for (int i = tid; i < L_LEN; i += 256) {
        atomicAdd(&S_re[b * L_LEN + i], aR[i]);
        atomicAdd(&S_im[b * L_LEN + i], aI[i]);
    }
}

// ---------------------------------------------------------------------------
// Kernel B: inverse FFT of S[b], real part * 1/(3072*512) -> mean_value[b][t]
// ---------------------------------------------------------------------------
__global__ __launch_bounds__(256) void ifft_kernel(
    const float* __restrict__ S_re, const float* __restrict__ S_im,
    float* __restrict__ mv)
{
    __shared__ float re[L_LEN], im[L_LEN];
    int b = blockIdx.x;
    int tid = threadIdx.x;
    #pragma unroll
    for (int it = 0; it < 12; it++) {
        int n = tid + (it << 8);
        int m = n / 3;
        int r = n - 3 * m;
        int dst = (r << 10) + (__brev((unsigned)m) >> 22);
        re[dst] = S_re[b * L_LEN + n];
        im[dst] = S_im[b * L_LEN + n];
    }
    __syncthreads();
    fft3072(re, im, tid, 1.0f);
    const float scale = 1.0f / (3072.0f * 512.0f);
    #pragma unroll
    for (int it = 0; it < 12; it++) {
        int t = tid + (it << 8);
        mv[b * L_LEN + t] = re[t] * scale;
    }
}

// ---------------------------------------------------------------------------
// Kernel C: per batch, top-40 (lowest-index tie-break, like lax.top_k) +
// softmax -> wts[b][40]; block 0 also writes the shift indices.
// ---------------------------------------------------------------------------
__global__ __launch_bounds__(256) void topk_kernel(
    const float* __restrict__ mv, float* __restrict__ wts, int* __restrict__ shifts)
{
    __shared__ float vals[L_LEN];
    __shared__ float rv[256];
    __shared__ int   ri[256];
    __shared__ float selv[TOPK];
    __shared__ int   seli[TOPK];
    int b = blockIdx.x;
    int tid = threadIdx.x;
    for (int i = tid; i < L_LEN; i += 256) vals[i] = mv[b * L_LEN + i];
    __syncthreads();
    for (int kk = 0; kk < TOPK; kk++) {
        float best = -INFINITY;
        int   bi   = 0x7fffffff;
        for (int i = tid; i < L_LEN; i += 256) {
            float vvv = vals[i];
            if (vvv > best || (vvv == best && i < bi)) { best = vvv; bi = i; }
        }
        rv[tid] = best; ri[tid] = bi;
        __syncthreads();
        for (int off = 128; off > 0; off >>= 1) {
            if (tid < off) {
                float ov = rv[tid + off]; int oi = ri[tid + off];
                if (ov > rv[tid] || (ov == rv[tid] && oi < ri[tid])) {
                    rv[tid] = ov; ri[tid] = oi;
                }
            }
            __syncthreads();
        }
        if (tid == 0) {
            selv[kk] = rv[0];
            seli[kk] = ri[0];
            vals[ri[0]] = -INFINITY;
        }
        __syncthreads();
    }
    if (tid == 0) {
        float mx = selv[0];
        float ex[TOPK];
        float sum = 0.0f;
        for (int kk = 0; kk < TOPK; kk++) { ex[kk] = __expf(selv[kk] - mx); sum += ex[kk]; }
        float inv = 1.0f / sum;
        for (int kk = 0; kk < TOPK; kk++) wts[b * TOPK + kk] = ex[kk] * inv;
        if (b == 0)
            for (int kk = 0; kk < TOPK; kk++) shifts[kk] = seli[kk];
    }
}

// ---------------------------------------------------------------------------
// Kernel D: out[b,t,:,:] = sum_k w[b,k] * v[b,(t+shift_k)%L,:,:]
// Block handles 2 rows of 512 floats (128 lanes x float4 each).
// blockIdx laid out so b = blockIdx % 8 -> per-batch XCD affinity for L2.
// ---------------------------------------------------------------------------
__global__ __launch_bounds__(256) void agg_kernel(
    const float* __restrict__ v, const float* __restrict__ wts,
    const int* __restrict__ shifts, float* __restrict__ out)
{
    __shared__ float w[TOPK];
    __shared__ int   sh[TOPK];
    int idx = blockIdx.x;
    int b   = idx & 7;
    int t0  = (idx >> 3) << 1;
    int tid = threadIdx.x;
    if (tid < TOPK) { w[tid] = wts[b * TOPK + tid]; sh[tid] = shifts[tid]; }
    __syncthreads();
    int row  = tid >> 7;          // 0..1
    int lane = tid & 127;         // 128 lanes * float4 = 512 floats
    int t = t0 + row;
    size_t vbase = (size_t)b * L_LEN * CH512;
    float4 acc = make_float4(0.0f, 0.0f, 0.0f, 0.0f);
    #pragma unroll 8
    for (int kk = 0; kk < TOPK; kk++) {
        int tt = t + sh[kk];
        if (tt >= L_LEN) tt -= L_LEN;
        const float4* p = (const float4*)(v + vbase + (size_t)tt * CH512);
        float4 x = p[lane];
        float ww = w[kk];
        acc.x += x.x * ww; acc.y += x.y * ww;
        acc.z += x.z * ww; acc.w += x.w * ww;
    }
    float4* po = (float4*)(out + vbase + (size_t)t * CH512);
    po[lane] = acc;
}

// ---------------------------------------------------------------------------
extern "C" void kernel_launch(void* const* d_in, const int* in_sizes, int n_in,
                              void* d_out, int out_size, void* d_ws, size_t ws_size,
                              hipStream_t stream)
{
    const float* q = (const float*)d_in[0];
    const float* k = (const float*)d_in[1];
    const float* v = (const float*)d_in[2];
    float* out = (float*)d_out;
    float* ws  = (float*)d_ws;

    // workspace layout (floats)
    float* S_re  = ws;                                  // 8*3072
    float* S_im  = ws + NBATCH * L_LEN;                 // 8*3072
    float* mv    = ws + 2 * NBATCH * L_LEN;             // 8*3072
    float* wts   = ws + 3 * NBATCH * L_LEN;             // 8*40
    int*   shifts = (int*)(ws + 3 * NBATCH * L_LEN + NBATCH * TOPK); // 40

    // zero the atomic accumulation buffers (ws is poisoned before every call)
    hipMemsetAsync(S_re, 0, (size_t)2 * NBATCH * L_LEN * sizeof(float), stream);

    corr_fft_kernel<<<dim3(512), dim3(256), 0, stream>>>(q, k, S_re, S_im);
    ifft_kernel<<<dim3(NBATCH), dim3(256), 0, stream>>>(S_re, S_im, mv);
    topk_kernel<<<dim3(NBATCH), dim3(256), 0, stream>>>(mv, wts, shifts);
    agg_kernel<<<dim3(NBATCH * L_LEN / 2), dim3(256), 0, stream>>>(v, wts, shifts, out);
}

// Round 2
// 502.205 us; speedup vs baseline: 1.7146x; 1.7146x over previous
//
#include <hip/hip_runtime.h>
#include <math.h>

#define L_LEN  3072
#define CH512  512
#define TOPK   40
#define NBATCH 8

// ---------------------------------------------------------------------------
// In-LDS 3072-point complex FFT: N = 3 x 1024.
// Input must be placed digit-reversed: x[3m+r] -> index r*1024 + bitrev10(m).
// After this routine, spectrum is in natural order.
// sgn = -1: forward (e^{-i...});  sgn = +1: inverse (unnormalized).
// Caller must have a __syncthreads() between writing re/im and calling this.
// ---------------------------------------------------------------------------
__device__ __forceinline__ void fft3072(float* re, float* im, int tid, float sgn)
{
    const float TWO_PI = 6.28318530717958647692f;
    // 10 radix-2 stages on the three independent 1024-point subarrays
    for (int s = 0; s < 10; s++) {
        int half = 1 << s;
        #pragma unroll
        for (int ii = 0; ii < 6; ii++) {
            int idx = tid + (ii << 8);          // 0..1535 : 1536 butterflies/stage
            int sub = idx >> 9;                 // which 1024-subarray
            int j   = idx & 511;                // butterfly within subarray
            int pos = j & (half - 1);
            int i0  = (sub << 10) + (((j >> s) << (s + 1)) | pos);
            int i1  = i0 + half;
            float ang = sgn * TWO_PI * (float)pos / (float)(half << 1);
            float c, sn;
            __sincosf(ang, &sn, &c);
            float br = re[i1], bi = im[i1];
            float tr = c * br - sn * bi;
            float ti = c * bi + sn * br;
            float ar = re[i0], ai = im[i0];
            re[i1] = ar - tr; im[i1] = ai - ti;
            re[i0] = ar + tr; im[i0] = ai + ti;
        }
        __syncthreads();
    }
    // radix-3 combine: X[k + 1024*j] = Y0[k] + w^j*(W1*Y1[k]) + w^{2j}*(W2*Y2[k])
    #pragma unroll
    for (int ii = 0; ii < 4; ii++) {
        int kk = tid + (ii << 8);               // 0..1023
        float ang1 = sgn * TWO_PI * (float)kk / 3072.0f;
        float c1, s1;
        __sincosf(ang1, &s1, &c1);
        float c2 = c1 * c1 - s1 * s1;           // W2 = W1^2
        float s2 = 2.0f * c1 * s1;
        float y0r = re[kk],        y0i = im[kk];
        float y1r = re[1024 + kk], y1i = im[1024 + kk];
        float y2r = re[2048 + kk], y2i = im[2048 + kk];
        float t1r = c1 * y1r - s1 * y1i, t1i = c1 * y1i + s1 * y1r;
        float t2r = c2 * y2r - s2 * y2i, t2i = c2 * y2i + s2 * y2r;
        float ur = t1r + t2r, ui = t1i + t2i;
        float vr = t1r - t2r, vi = t1i - t2i;
        float mr = y0r - 0.5f * ur, mi = y0i - 0.5f * ui;
        float s3 = sgn * 0.86602540378443864676f;
        re[kk]        = y0r + ur;       im[kk]        = y0i + ui;
        re[1024 + kk] = mr - s3 * vi;   im[1024 + kk] = mi + s3 * vr;
        re[2048 + kk] = mr + s3 * vi;   im[2048 + kk] = mi - s3 * vr;
    }
    __syncthreads();
}

// ---------------------------------------------------------------------------
// Transpose kernel: [B, L, C] -> [B, C, L] for q (dst0) and k (dst1).
// 32x32 tiles via LDS (pad +1). blockIdx.z = b*2 + (0=q,1=k).
// Fully coalesced on both sides.
// ---------------------------------------------------------------------------
__global__ __launch_bounds__(256) void transpose_kernel(
    const float* __restrict__ q, const float* __restrict__ k,
    float* __restrict__ qT, float* __restrict__ kT)
{
    __shared__ float tile[32][33];
    int which = blockIdx.z & 1;
    int b     = blockIdx.z >> 1;
    int l0    = blockIdx.x << 5;
    int c0    = blockIdx.y << 5;
    int x = threadIdx.x & 31;
    int y = threadIdx.x >> 5;        // 0..7
    const float* src = which ? k : q;
    float* dst       = which ? kT : qT;
    size_t in_base = (size_t)b * L_LEN * CH512;
    #pragma unroll
    for (int i = 0; i < 4; i++) {
        int ly = y + (i << 3);
        tile[ly][x] = src[in_base + (size_t)(l0 + ly) * CH512 + c0 + x];
    }
    __syncthreads();
    size_t out_base = (size_t)b * CH512 * L_LEN;
    #pragma unroll
    for (int i = 0; i < 4; i++) {
        int cy = y + (i << 3);
        dst[out_base + (size_t)(c0 + cy) * L_LEN + l0 + x] = tile[x][cy];
    }
}

// ---------------------------------------------------------------------------
// Kernel A: per (b, h, e-group of 8): packed FFT z = q + i*k, extract
// P[f] = Q[f]*conj(K[f]) via Hermitian split, accumulate over 8 channels in
// LDS, then atomically add into the per-batch spectrum sum S[b].
// Inputs are TRANSPOSED [B, C, L] -> contiguous float4 series loads.
// Grid: 512 blocks = B(8) * H(8) * egroups(8). 256 threads.
// ---------------------------------------------------------------------------
__global__ __launch_bounds__(256) void corr_fft_kernel(
    const float* __restrict__ qT, const float* __restrict__ kT,
    float* __restrict__ S_re, float* __restrict__ S_im)
{
    __shared__ float re[L_LEN], im[L_LEN], aR[L_LEN], aI[L_LEN];
    int blk = blockIdx.x;
    int b   = blk >> 6;          // /64
    int rem = blk & 63;
    int h   = rem >> 3;
    int eg  = rem & 7;
    int tid = threadIdx.x;

    for (int i = tid; i < L_LEN; i += 256) { aR[i] = 0.0f; aI[i] = 0.0f; }

    for (int ec = 0; ec < 8; ec++) {
        int e = (eg << 3) + ec;
        size_t ch_off = ((size_t)b * CH512 + h * 64 + e) * L_LEN;
        const float4* q4 = (const float4*)(qT + ch_off);
        const float4* k4 = (const float4*)(kT + ch_off);
        __syncthreads();   // previous channel's readers of re/im are done (also covers aR init)
        #pragma unroll
        for (int it = 0; it < 3; it++) {
            int idx = tid + (it << 8);          // 0..767 float4s
            float4 xq = q4[idx];
            float4 xk = k4[idx];
            #pragma unroll
            for (int j = 0; j < 4; j++) {
                int n = (idx << 2) + j;
                int m = n / 3;
                int r = n - 3 * m;
                int dst = (r << 10) + (__brev((unsigned)m) >> 22);
                float qv = (j == 0) ? xq.x : (j == 1) ? xq.y : (j == 2) ? xq.z : xq.w;
                float kv = (j == 0) ? xk.x : (j == 1) ? xk.y : (j == 2) ? xk.z : xk.w;
                re[dst] = qv;
                im[dst] = kv;
            }
        }
        __syncthreads();
        fft3072(re, im, tid, -1.0f);
        // P = (i/4) * (A+B) * conj(A-B),  A = Z[f], B = conj(Z[(N-f)%N])
        #pragma unroll
        for (int it = 0; it < 12; it++) {
            int f = tid + (it << 8);
            int g = (f == 0) ? 0 : (L_LEN - f);
            float ar = re[f], ai = im[f];
            float br = re[g], bi = -im[g];
            float ur = ar + br, ui = ai + bi;
            float vr = ar - br, vi = ai - bi;
            aR[f] += 0.25f * (ur * vi - ui * vr);
            aI[f] += 0.25f * (ur * vr + ui * vi);
        }
    }
    __syncthreads();
    for (int i = tid; i < L_LEN; i += 256) {
        atomicAdd(&S_re[b * L_LEN + i], aR[i]);
        atomicAdd(&S_im[b * L_LEN + i], aI[i]);
    }
}

// ---------------------------------------------------------------------------
// Kernel B: inverse FFT of S[b], real part * 1/(3072*512) -> mean_value[b][t]
// ---------------------------------------------------------------------------
__global__ __launch_bounds__(256) void ifft_kernel(
    const float* __restrict__ S_re, const float* __restrict__ S_im,
    float* __restrict__ mv)
{
    __shared__ float re[L_LEN], im[L_LEN];
    int b = blockIdx.x;
    int tid = threadIdx.x;
    #pragma unroll
    for (int it = 0; it < 12; it++) {
        int n = tid + (it << 8);
        int m = n / 3;
        int r = n - 3 * m;
        int dst = (r << 10) + (__brev((unsigned)m) >> 22);
        re[dst] = S_re[b * L_LEN + n];
        im[dst] = S_im[b * L_LEN + n];
    }
    __syncthreads();
    fft3072(re, im, tid, 1.0f);
    const float scale = 1.0f / (3072.0f * 512.0f);
    #pragma unroll
    for (int it = 0; it < 12; it++) {
        int t = tid + (it << 8);
        mv[b * L_LEN + t] = re[t] * scale;
    }
}

// ---------------------------------------------------------------------------
// Kernel C: per batch, top-40 (lowest-index tie-break, like lax.top_k) +
// softmax -> wts[b][40]; block 0 also writes the shift indices.
// ---------------------------------------------------------------------------
__global__ __launch_bounds__(256) void topk_kernel(
    const float* __restrict__ mv, float* __restrict__ wts, int* __restrict__ shifts)
{
    __shared__ float vals[L_LEN];
    __shared__ float rv[256];
    __shared__ int   ri[256];
    __shared__ float selv[TOPK];
    __shared__ int   seli[TOPK];
    int b = blockIdx.x;
    int tid = threadIdx.x;
    for (int i = tid; i < L_LEN; i += 256) vals[i] = mv[b * L_LEN + i];
    __syncthreads();
    for (int kk = 0; kk < TOPK; kk++) {
        float best = -INFINITY;
        int   bi   = 0x7fffffff;
        for (int i = tid; i < L_LEN; i += 256) {
            float vvv = vals[i];
            if (vvv > best || (vvv == best && i < bi)) { best = vvv; bi = i; }
        }
        rv[tid] = best; ri[tid] = bi;
        __syncthreads();
        for (int off = 128; off > 0; off >>= 1) {
            if (tid < off) {
                float ov = rv[tid + off]; int oi = ri[tid + off];
                if (ov > rv[tid] || (ov == rv[tid] && oi < ri[tid])) {
                    rv[tid] = ov; ri[tid] = oi;
                }
            }
            __syncthreads();
        }
        if (tid == 0) {
            selv[kk] = rv[0];
            seli[kk] = ri[0];
            vals[ri[0]] = -INFINITY;
        }
        __syncthreads();
    }
    if (tid == 0) {
        float mx = selv[0];
        float ex[TOPK];
        float sum = 0.0f;
        for (int kk = 0; kk < TOPK; kk++) { ex[kk] = __expf(selv[kk] - mx); sum += ex[kk]; }
        float inv = 1.0f / sum;
        for (int kk = 0; kk < TOPK; kk++) wts[b * TOPK + kk] = ex[kk] * inv;
        if (b == 0)
            for (int kk = 0; kk < TOPK; kk++) shifts[kk] = seli[kk];
    }
}

// ---------------------------------------------------------------------------
// Kernel D: out[b,t,:,:] = sum_k w[b,k] * v[b,(t+shift_k)%L,:,:]
// Block handles 2 rows of 512 floats (128 lanes x float4 each).
// blockIdx laid out so b = blockIdx % 8 -> per-batch XCD affinity for L2.
// ---------------------------------------------------------------------------
__global__ __launch_bounds__(256) void agg_kernel(
    const float* __restrict__ v, const float* __restrict__ wts,
    const int* __restrict__ shifts, float* __restrict__ out)
{
    __shared__ float w[TOPK];
    __shared__ int   sh[TOPK];
    int idx = blockIdx.x;
    int b   = idx & 7;
    int t0  = (idx >> 3) << 1;
    int tid = threadIdx.x;
    if (tid < TOPK) { w[tid] = wts[b * TOPK + tid]; sh[tid] = shifts[tid]; }
    __syncthreads();
    int row  = tid >> 7;          // 0..1
    int lane = tid & 127;         // 128 lanes * float4 = 512 floats
    int t = t0 + row;
    size_t vbase = (size_t)b * L_LEN * CH512;
    float4 acc = make_float4(0.0f, 0.0f, 0.0f, 0.0f);
    #pragma unroll 8
    for (int kk = 0; kk < TOPK; kk++) {
        int tt = t + sh[kk];
        if (tt >= L_LEN) tt -= L_LEN;
        const float4* p = (const float4*)(v + vbase + (size_t)tt * CH512);
        float4 x = p[lane];
        float ww = w[kk];
        acc.x += x.x * ww; acc.y += x.y * ww;
        acc.z += x.z * ww; acc.w += x.w * ww;
    }
    float4* po = (float4*)(out + vbase + (size_t)t * CH512);
    po[lane] = acc;
}

// ---------------------------------------------------------------------------
extern "C" void kernel_launch(void* const* d_in, const int* in_sizes, int n_in,
                              void* d_out, int out_size, void* d_ws, size_t ws_size,
                              hipStream_t stream)
{
    const float* q = (const float*)d_in[0];
    const float* k = (const float*)d_in[1];
    const float* v = (const float*)d_in[2];
    float* out = (float*)d_out;
    float* ws  = (float*)d_ws;

    const size_t TSZ = (size_t)NBATCH * CH512 * L_LEN;   // 12.58M floats

    // qT uses d_out as scratch (agg overwrites it at the end of the stream);
    // kT + small buffers live in d_ws (~50.6 MB needed).
    float* qT = out;
    float* kT = ws;
    float* S_re = ws + TSZ;                              // 8*3072
    float* S_im = S_re + NBATCH * L_LEN;                 // 8*3072
    float* mv   = S_im + NBATCH * L_LEN;                 // 8*3072
    float* wts  = mv + NBATCH * L_LEN;                   // 8*40
    int*   shifts = (int*)(wts + NBATCH * TOPK);         // 40

    // zero the atomic accumulation buffers (ws is poisoned before every call)
    hipMemsetAsync(S_re, 0, (size_t)2 * NBATCH * L_LEN * sizeof(float), stream);

    transpose_kernel<<<dim3(L_LEN / 32, CH512 / 32, NBATCH * 2), dim3(256), 0, stream>>>(
        q, k, qT, kT);
    corr_fft_kernel<<<dim3(512), dim3(256), 0, stream>>>(qT, kT, S_re, S_im);
    ifft_kernel<<<dim3(NBATCH), dim3(256), 0, stream>>>(S_re, S_im, mv);
    topk_kernel<<<dim3(NBATCH), dim3(256), 0, stream>>>(mv, wts, shifts);
    agg_kernel<<<dim3(NBATCH * L_LEN / 2), dim3(256), 0, stream>>>(v, wts, shifts, out);
}

// Round 4
// 455.785 us; speedup vs baseline: 1.8892x; 1.1018x over previous
//
#include <hip/hip_runtime.h>
#include <math.h>

#define L_LEN  3072
#define CH512  512
#define TOPK   40
#define NBATCH 8
#define TWSZ   1632   // 1536 entries + swizzle pad (phys = j + (j>>4), max 1630)

// ---------------------------------------------------------------------------
// In-LDS 3072-point complex FFT: N = 3 x 1024, twiddles from LDS table.
// Ctab[j + (j>>4)] = cos(2*pi*j/3072), Stab likewise sin, j in [0,1536).
// Input must be placed digit-reversed: x[3m+r] -> index r*1024 + bitrev10(m).
// sgn = -1: forward;  sgn = +1: inverse (unnormalized).
// Caller must __syncthreads() between writing re/im (and tables) and calling.
// ---------------------------------------------------------------------------
__device__ __forceinline__ void fft3072(float* re, float* im,
                                        const float* Ctab, const float* Stab,
                                        int tid, float sgn)
{
    // 10 radix-2 stages on the three independent 1024-point subarrays
    for (int s = 0; s < 10; s++) {
        int half = 1 << s;
        #pragma unroll
        for (int ii = 0; ii < 6; ii++) {
            int idx = tid + (ii << 8);          // 0..1535 : 1536 butterflies/stage
            int sub = idx >> 9;                 // which 1024-subarray
            int j   = idx & 511;                // butterfly within subarray
            int pos = j & (half - 1);
            int i0  = (sub << 10) + (((j >> s) << (s + 1)) | pos);
            int i1  = i0 + half;
            int tw  = 3 * (pos << (9 - s));     // angle = 2*pi*tw/3072
            int ph  = tw + (tw >> 4);
            float c  = Ctab[ph];
            float sn = sgn * Stab[ph];
            float br = re[i1], bi = im[i1];
            float tr = c * br - sn * bi;
            float ti = c * bi + sn * br;
            float ar = re[i0], ai = im[i0];
            re[i1] = ar - tr; im[i1] = ai - ti;
            re[i0] = ar + tr; im[i0] = ai + ti;
        }
        __syncthreads();
    }
    // radix-3 combine
    #pragma unroll
    for (int ii = 0; ii < 4; ii++) {
        int kk = tid + (ii << 8);               // 0..1023
        int ph = kk + (kk >> 4);
        float c1 = Ctab[ph];
        float s1 = sgn * Stab[ph];
        float c2 = c1 * c1 - s1 * s1;           // W2 = W1^2
        float s2 = 2.0f * c1 * s1;
        float y0r = re[kk],        y0i = im[kk];
        float y1r = re[1024 + kk], y1i = im[1024 + kk];
        float y2r = re[2048 + kk], y2i = im[2048 + kk];
        float t1r = c1 * y1r - s1 * y1i, t1i = c1 * y1i + s1 * y1r;
        float t2r = c2 * y2r - s2 * y2i, t2i = c2 * y2i + s2 * y2r;
        float ur = t1r + t2r, ui = t1i + t2i;
        float vr = t1r - t2r, vi = t1i - t2i;
        float mr = y0r - 0.5f * ur, mi = y0i - 0.5f * ui;
        float s3 = sgn * 0.86602540378443864676f;
        re[kk]        = y0r + ur;       im[kk]        = y0i + ui;
        re[1024 + kk] = mr - s3 * vi;   im[1024 + kk] = mi + s3 * vr;
        re[2048 + kk] = mr + s3 * vi;   im[2048 + kk] = mi - s3 * vr;
    }
    __syncthreads();
}

__device__ __forceinline__ void fill_twiddles(float* Ctab, float* Stab, int tid)
{
    const float TWO_PI = 6.28318530717958647692f;
    for (int j = tid; j < 1536; j += 256) {
        float ang = TWO_PI * (float)j / 3072.0f;
        float c, s;
        __sincosf(ang, &s, &c);
        int ph = j + (j >> 4);
        Ctab[ph] = c; Stab[ph] = s;
    }
}

// ---------------------------------------------------------------------------
// Transpose kernel: [B, L, C] -> [B, C, L] for q and k. 32x32 LDS tiles.
// ---------------------------------------------------------------------------
__global__ __launch_bounds__(256) void transpose_kernel(
    const float* __restrict__ q, const float* __restrict__ k,
    float* __restrict__ qT, float* __restrict__ kT)
{
    __shared__ float tile[32][33];
    int which = blockIdx.z & 1;
    int b     = blockIdx.z >> 1;
    int l0    = blockIdx.x << 5;
    int c0    = blockIdx.y << 5;
    int x = threadIdx.x & 31;
    int y = threadIdx.x >> 5;
    const float* src = which ? k : q;
    float* dst       = which ? kT : qT;
    size_t in_base = (size_t)b * L_LEN * CH512;
    #pragma unroll
    for (int i = 0; i < 4; i++) {
        int ly = y + (i << 3);
        tile[ly][x] = src[in_base + (size_t)(l0 + ly) * CH512 + c0 + x];
    }
    __syncthreads();
    size_t out_base = (size_t)b * CH512 * L_LEN;
    #pragma unroll
    for (int i = 0; i < 4; i++) {
        int cy = y + (i << 3);
        dst[out_base + (size_t)(c0 + cy) * L_LEN + l0 + x] = tile[x][cy];
    }
}

// ---------------------------------------------------------------------------
// Kernel A: per (b, h, e-group of 8): packed FFT z = q + i*k, extract
// P = Q*conj(K) via Hermitian split, accumulate 8 channels in LDS, atomadd
// into per-batch spectrum S[b]. Inputs transposed [B, C, L].
// ---------------------------------------------------------------------------
__global__ __launch_bounds__(256) void corr_fft_kernel(
    const float* __restrict__ qT, const float* __restrict__ kT,
    float* __restrict__ S_re, float* __restrict__ S_im)
{
    __shared__ float re[L_LEN], im[L_LEN], aR[L_LEN], aI[L_LEN];
    __shared__ float Ctab[TWSZ], Stab[TWSZ];
    int blk = blockIdx.x;
    int b   = blk >> 6;
    int rem = blk & 63;
    int h   = rem >> 3;
    int eg  = rem & 7;
    int tid = threadIdx.x;

    fill_twiddles(Ctab, Stab, tid);
    for (int i = tid; i < L_LEN; i += 256) { aR[i] = 0.0f; aI[i] = 0.0f; }

    for (int ec = 0; ec < 8; ec++) {
        int e = (eg << 3) + ec;
        size_t ch_off = ((size_t)b * CH512 + h * 64 + e) * L_LEN;
        const float4* q4 = (const float4*)(qT + ch_off);
        const float4* k4 = (const float4*)(kT + ch_off);
        __syncthreads();   // prev channel readers done; also covers init/table fill
        #pragma unroll
        for (int it = 0; it < 3; it++) {
            int idx = tid + (it << 8);
            float4 xq = q4[idx];
            float4 xk = k4[idx];
            #pragma unroll
            for (int j = 0; j < 4; j++) {
                int n = (idx << 2) + j;
                int m = n / 3;
                int r = n - 3 * m;
                int dst = (r << 10) + (__brev((unsigned)m) >> 22);
                float qv = (j == 0) ? xq.x : (j == 1) ? xq.y : (j == 2) ? xq.z : xq.w;
                float kv = (j == 0) ? xk.x : (j == 1) ? xk.y : (j == 2) ? xk.z : xk.w;
                re[dst] = qv;
                im[dst] = kv;
            }
        }
        __syncthreads();
        fft3072(re, im, Ctab, Stab, tid, -1.0f);
        // P = (i/4) * (A+B) * conj(A-B)
        #pragma unroll
        for (int it = 0; it < 12; it++) {
            int f = tid + (it << 8);
            int g = (f == 0) ? 0 : (L_LEN - f);
            float ar = re[f], ai = im[f];
            float br = re[g], bi = -im[g];
            float ur = ar + br, ui = ai + bi;
            float vr = ar - br, vi = ai - bi;
            aR[f] += 0.25f * (ur * vi - ui * vr);
            aI[f] += 0.25f * (ur * vr + ui * vi);
        }
    }
    __syncthreads();
    for (int i = tid; i < L_LEN; i += 256) {
        atomicAdd(&S_re[b * L_LEN + i], aR[i]);
        atomicAdd(&S_im[b * L_LEN + i], aI[i]);
    }
}

// ---------------------------------------------------------------------------
// Fused kernel B+C: inverse FFT of S[b] -> mean_value in LDS -> top-40
// (lowest-index tie-break) -> softmax -> wts[b]; block 0 writes shifts.
// ---------------------------------------------------------------------------
__global__ __launch_bounds__(256) void ifft_topk_kernel(
    const float* __restrict__ S_re, const float* __restrict__ S_im,
    float* __restrict__ wts, int* __restrict__ shifts)
{
    __shared__ float re[L_LEN], im[L_LEN];
    __shared__ float Ctab[TWSZ], Stab[TWSZ];
    __shared__ float vals[L_LEN];
    __shared__ float rv[4];
    __shared__ int   ri[4];
    __shared__ float selv[TOPK];
    __shared__ int   seli[TOPK];
    int b = blockIdx.x;
    int tid = threadIdx.x;
    fill_twiddles(Ctab, Stab, tid);
    #pragma unroll
    for (int it = 0; it < 12; it++) {
        int n = tid + (it << 8);
        int m = n / 3;
        int r = n - 3 * m;
        int dst = (r << 10) + (__brev((unsigned)m) >> 22);
        re[dst] = S_re[b * L_LEN + n];
        im[dst] = S_im[b * L_LEN + n];
    }
    __syncthreads();
    fft3072(re, im, Ctab, Stab, tid, 1.0f);
    const float scale = 1.0f / (3072.0f * 512.0f);
    #pragma unroll
    for (int it = 0; it < 12; it++) {
        int t = tid + (it << 8);
        vals[t] = re[t] * scale;
    }
    __syncthreads();

    int wave = tid >> 6;
    int lane = tid & 63;
    for (int kk = 0; kk < TOPK; kk++) {
        float best = -INFINITY;
        int   bi   = 0x7fffffff;
        for (int i = tid; i < L_LEN; i += 256) {
            float vvv = vals[i];
            if (vvv > best || (vvv == best && i < bi)) { best = vvv; bi = i; }
        }
        #pragma unroll
        for (int off = 32; off > 0; off >>= 1) {
            float ov = __shfl_down(best, off);
            int   oi = __shfl_down(bi,  off);
            if (ov > best || (ov == best && oi < bi)) { best = ov; bi = oi; }
        }
        if (lane == 0) { rv[wave] = best; ri[wave] = bi; }
        __syncthreads();
        if (tid == 0) {
            float bv = rv[0]; int bj = ri[0];
            #pragma unroll
            for (int wv = 1; wv < 4; wv++) {
                if (rv[wv] > bv || (rv[wv] == bv && ri[wv] < bj)) { bv = rv[wv]; bj = ri[wv]; }
            }
            selv[kk] = bv; seli[kk] = bj;
            vals[bj] = -INFINITY;
        }
        __syncthreads();
    }
    if (tid == 0) {
        float mx = selv[0];
        float sum = 0.0f;
        float ex[TOPK];
        for (int kk = 0; kk < TOPK; kk++) { ex[kk] = __expf(selv[kk] - mx); sum += ex[kk]; }
        float inv = 1.0f / sum;
        for (int kk = 0; kk < TOPK; kk++) wts[b * TOPK + kk] = ex[kk] * inv;
        if (b == 0)
            for (int kk = 0; kk < TOPK; kk++) shifts[kk] = seli[kk];
    }
}

// ---------------------------------------------------------------------------
// Kernel D: out[b,t,ch] = sum_k w[b,k] * v[b,(t+s_k)%L,ch]
// L2-resident channel-slab tiling: chunk = (b, 64-ch slab) has working set
// 3072*256B = 786 KB << 4 MiB XCD L2. Block = (chunk, 16-row t-tile).
// blockIdx = slab + 8*(tile + 192*b): idx%8 == slab -> one chunk per XCD
// at a time (round-robin XCD mapping heuristic; correctness unaffected).
// ---------------------------------------------------------------------------
__global__ __launch_bounds__(256) void agg_kernel(
    const float* __restrict__ v, const float* __restrict__ wts,
    const int* __restrict__ shifts, float* __restrict__ out)
{
    __shared__ float w[TOPK];
    __shared__ int   sh[TOPK];
    int idx  = blockIdx.x;
    int slab = idx & 7;
    int rest = idx >> 3;
    int tile = rest % 192;
    int b    = rest / 192;
    int tid  = threadIdx.x;
    if (tid < TOPK) { w[tid] = wts[b * TOPK + tid]; sh[tid] = shifts[tid]; }
    __syncthreads();
    int t  = (tile << 4) + (tid >> 4);             // 16 rows per block
    int ch = (slab << 6) + ((tid & 15) << 2);      // 64-ch slab, float4 per lane
    size_t vbase = (size_t)b * L_LEN * CH512;
    float4 acc = make_float4(0.0f, 0.0f, 0.0f, 0.0f);
    #pragma unroll 8
    for (int kk = 0; kk < TOPK; kk++) {
        int tt = t + sh[kk];
        if (tt >= L_LEN) tt -= L_LEN;
        const float4 x = *(const float4*)(v + vbase + (size_t)tt * CH512 + ch);
        float ww = w[kk];
        acc.x += x.x * ww; acc.y += x.y * ww;
        acc.z += x.z * ww; acc.w += x.w * ww;
    }
    *(float4*)(out + vbase + (size_t)t * CH512 + ch) = acc;
}

// ---------------------------------------------------------------------------
extern "C" void kernel_launch(void* const* d_in, const int* in_sizes, int n_in,
                              void* d_out, int out_size, void* d_ws, size_t ws_size,
                              hipStream_t stream)
{
    const float* q = (const float*)d_in[0];
    const float* k = (const float*)d_in[1];
    const float* v = (const float*)d_in[2];
    float* out = (float*)d_out;
    float* ws  = (float*)d_ws;

    const size_t TSZ = (size_t)NBATCH * CH512 * L_LEN;   // 12.58M floats

    // qT uses d_out as scratch (agg overwrites it last); kT + small bufs in ws.
    float* qT = out;
    float* kT = ws;
    float* S_re = ws + TSZ;                              // 8*3072
    float* S_im = S_re + NBATCH * L_LEN;                 // 8*3072
    float* wts  = S_im + NBATCH * L_LEN;                 // 8*40
    int*   shifts = (int*)(wts + NBATCH * TOPK);         // 40

    hipMemsetAsync(S_re, 0, (size_t)2 * NBATCH * L_LEN * sizeof(float), stream);

    transpose_kernel<<<dim3(L_LEN / 32, CH512 / 32, NBATCH * 2), dim3(256), 0, stream>>>(
        q, k, qT, kT);
    corr_fft_kernel<<<dim3(512), dim3(256), 0, stream>>>(qT, kT, S_re, S_im);
    ifft_topk_kernel<<<dim3(NBATCH), dim3(256), 0, stream>>>(S_re, S_im, wts, shifts);
    // grid: 8 slabs * 192 t-tiles * 8 batches = 12288 blocks
    agg_kernel<<<dim3(8 * (L_LEN / 16) * NBATCH), dim3(256), 0, stream>>>(v, wts, shifts, out);
}

// Round 5
// 424.017 us; speedup vs baseline: 2.0308x; 1.0749x over previous
//
#include <hip/hip_runtime.h>
#include <math.h>

#define L_LEN  3072
#define CH512  512
#define TOPK   40
#define NBATCH 8
#define TWSZ   1088            // 1024 twiddles + swizzle pad (ph = j + (j>>4), max 1086)
#define SW(i)  ((i) + ((i) >> 5))   // LDS bank-conflict swizzle for re/im
#define FFTSZ  3168            // SW(3071) = 3166 -> round up

// ---------------------------------------------------------------------------
// In-LDS 3072-point complex FFT: N = 3 x 1024, radix-4 (fused radix-2 pairs)
// + radix-3 combine. re/im are SW-swizzled arrays of FFTSZ floats.
// Input must be placed at SW(r*1024 + brev10(m)) for x[3m+r].
// Twiddles: Ctab/Stab[j + (j>>4)] = cos/sin(2*pi*j/3072), j in [0,1024).
// sgn = -1 forward, +1 inverse (unnormalized). Output natural order (SW'd).
// Caller must __syncthreads() after writing re/im before calling.
// ---------------------------------------------------------------------------
__device__ __forceinline__ void fft3072(float* re, float* im,
                                        const float* Ctab, const float* Stab,
                                        int tid, float sgn)
{
    // 5 fused double-stages: s = 0,2,4,6,8 on the three 1024-subarrays
    #pragma unroll
    for (int s = 0; s < 10; s += 2) {
        int q = 1 << s;
        #pragma unroll
        for (int ii = 0; ii < 3; ii++) {
            int ib  = tid + (ii << 8);          // 0..767 butterflies
            int sub = ib >> 8;
            int t   = ib & 255;
            int pos = t & (q - 1);
            int base= t >> s;
            int i0  = (sub << 10) + (base << (s + 2)) + pos;
            int p0 = SW(i0), p1 = SW(i0 + q), p2 = SW(i0 + 2*q), p3 = SW(i0 + 3*q);
            int j2 = 3 * (pos << (8 - s));      // T2 angle index (2*pi*j2/3072)
            int ph = j2 + (j2 >> 4);
            float c2 = Ctab[ph], s2 = sgn * Stab[ph];
            float c1 = c2*c2 - s2*s2, s1 = 2.0f*c2*s2;     // T1 = T2^2
            float a0r = re[p0], a0i = im[p0];
            float a1r = re[p1], a1i = im[p1];
            float a2r = re[p2], a2i = im[p2];
            float a3r = re[p3], a3i = im[p3];
            // stage s: pairs (0,1) and (2,3), twiddle T1
            float t1r = c1*a1r - s1*a1i, t1i = c1*a1i + s1*a1r;
            float u0r = a0r + t1r, u0i = a0i + t1i;
            float u1r = a0r - t1r, u1i = a0i - t1i;
            float t3r = c1*a3r - s1*a3i, t3i = c1*a3i + s1*a3r;
            float u2r = a2r + t3r, u2i = a2i + t3i;
            float u3r = a2r - t3r, u3i = a2i - t3i;
            // stage s+1: pairs (0,2) twiddle T2; (1,3) twiddle sgn*i*T2
            float w2r = c2*u2r - s2*u2i, w2i = c2*u2i + s2*u2r;
            float w3r = c2*u3r - s2*u3i, w3i = c2*u3i + s2*u3r;
            float iw3r = -sgn * w3i, iw3i = sgn * w3r;
            re[p0] = u0r + w2r;  im[p0] = u0i + w2i;
            re[p2] = u0r - w2r;  im[p2] = u0i - w2i;
            re[p1] = u1r + iw3r; im[p1] = u1i + iw3i;
            re[p3] = u1r - iw3r; im[p3] = u1i - iw3i;
        }
        __syncthreads();
    }
    // radix-3 combine: X[k+1024j] from Y0,Y1,Y2
    #pragma unroll
    for (int ii = 0; ii < 4; ii++) {
        int kk = tid + (ii << 8);               // 0..1023
        int ph = kk + (kk >> 4);
        float c1 = Ctab[ph];
        float s1 = sgn * Stab[ph];
        float c2 = c1*c1 - s1*s1;               // W2 = W1^2
        float s2 = 2.0f*c1*s1;
        int pk0 = SW(kk), pk1 = SW(1024 + kk), pk2 = SW(2048 + kk);
        float y0r = re[pk0], y0i = im[pk0];
        float y1r = re[pk1], y1i = im[pk1];
        float y2r = re[pk2], y2i = im[pk2];
        float t1r = c1*y1r - s1*y1i, t1i = c1*y1i + s1*y1r;
        float t2r = c2*y2r - s2*y2i, t2i = c2*y2i + s2*y2r;
        float ur = t1r + t2r, ui = t1i + t2i;
        float vr = t1r - t2r, vi = t1i - t2i;
        float mr = y0r - 0.5f*ur, mi = y0i - 0.5f*ui;
        float s3 = sgn * 0.86602540378443864676f;
        re[pk0] = y0r + ur;      im[pk0] = y0i + ui;
        re[pk1] = mr - s3*vi;    im[pk1] = mi + s3*vr;
        re[pk2] = mr + s3*vi;    im[pk2] = mi - s3*vr;
    }
    __syncthreads();
}

__device__ __forceinline__ void fill_twiddles(float* Ctab, float* Stab, int tid)
{
    const float TWO_PI = 6.28318530717958647692f;
    for (int j = tid; j < 1024; j += 256) {
        float ang = TWO_PI * (float)j / 3072.0f;
        float c, s;
        __sincosf(ang, &s, &c);
        int ph = j + (j >> 4);
        Ctab[ph] = c; Stab[ph] = s;
    }
}

// ---------------------------------------------------------------------------
// Transpose kernel: [B, L, C] -> [B, C, L] for q and k. 64x64 tiles, float4
// loads and stores (256 B contiguous per 16 lanes). blockIdx.z = b*2 + which.
// ---------------------------------------------------------------------------
__global__ __launch_bounds__(256) void transpose_kernel(
    const float* __restrict__ q, const float* __restrict__ k,
    float* __restrict__ qT, float* __restrict__ kT)
{
    __shared__ float tile[64][65];
    int which = blockIdx.z & 1;
    int b     = blockIdx.z >> 1;
    int l0    = blockIdx.x << 6;
    int c0    = blockIdx.y << 6;
    int x4 = threadIdx.x & 15;          // float4 column
    int y  = threadIdx.x >> 4;          // 0..15
    const float* src = which ? k : q;
    float* dst       = which ? kT : qT;
    size_t in_base = (size_t)b * L_LEN * CH512;
    #pragma unroll
    for (int p = 0; p < 4; p++) {
        int r = y + (p << 4);
        float4 v = *(const float4*)(src + in_base + (size_t)(l0 + r) * CH512 + c0 + (x4 << 2));
        tile[r][(x4 << 2) + 0] = v.x;
        tile[r][(x4 << 2) + 1] = v.y;
        tile[r][(x4 << 2) + 2] = v.z;
        tile[r][(x4 << 2) + 3] = v.w;
    }
    __syncthreads();
    size_t out_base = (size_t)b * CH512 * L_LEN;
    #pragma unroll
    for (int p = 0; p < 4; p++) {
        int c = y + (p << 4);
        float4 w;
        w.x = tile[(x4 << 2) + 0][c];
        w.y = tile[(x4 << 2) + 1][c];
        w.z = tile[(x4 << 2) + 2][c];
        w.w = tile[(x4 << 2) + 3][c];
        *(float4*)(dst + out_base + (size_t)(c0 + c) * L_LEN + l0 + (x4 << 2)) = w;
    }
}

// ---------------------------------------------------------------------------
// Kernel A: per (b, channel-octet): packed FFT z = q + i*k per channel,
// extract P = Q*conj(K) via Hermitian split, accumulate 8 channels in
// REGISTERS (12 re + 12 im per thread), one atomicAdd pass into S[b].
// Inputs transposed [B, C, L]. LDS ~34 KB -> 4 blocks/CU.
// ---------------------------------------------------------------------------
__global__ __launch_bounds__(256, 4) void corr_fft_kernel(
    const float* __restrict__ qT, const float* __restrict__ kT,
    float* __restrict__ S_re, float* __restrict__ S_im)
{
    __shared__ float re[FFTSZ], im[FFTSZ];
    __shared__ float Ctab[TWSZ], Stab[TWSZ];
    int blk = blockIdx.x;
    int b   = blk >> 6;
    int c0  = (blk & 63) << 3;     // channel octet base
    int tid = threadIdx.x;

    fill_twiddles(Ctab, Stab, tid);

    float accR[12], accI[12];
    #pragma unroll
    for (int it = 0; it < 12; it++) { accR[it] = 0.0f; accI[it] = 0.0f; }

    for (int ec = 0; ec < 8; ec++) {
        size_t ch_off = ((size_t)b * CH512 + c0 + ec) * L_LEN;
        const float4* q4 = (const float4*)(qT + ch_off);
        const float4* k4 = (const float4*)(kT + ch_off);
        __syncthreads();   // re/im free (covers table fill on ec==0, extract otherwise)
        #pragma unroll
        for (int it = 0; it < 3; it++) {
            int idx = tid + (it << 8);
            float4 xq = q4[idx];
            float4 xk = k4[idx];
            #pragma unroll
            for (int j = 0; j < 4; j++) {
                int n = (idx << 2) + j;
                int m = n / 3;
                int r = n - 3 * m;
                int dst = SW((r << 10) + (__brev((unsigned)m) >> 22));
                float qv = (j == 0) ? xq.x : (j == 1) ? xq.y : (j == 2) ? xq.z : xq.w;
                float kv = (j == 0) ? xk.x : (j == 1) ? xk.y : (j == 2) ? xk.z : xk.w;
                re[dst] = qv;
                im[dst] = kv;
            }
        }
        __syncthreads();
        fft3072(re, im, Ctab, Stab, tid, -1.0f);
        // P = (i/4) * (A+B) * conj(A-B),  A = Z[f], B = conj(Z[(N-f)%N])
        #pragma unroll
        for (int it = 0; it < 12; it++) {
            int f = tid + (it << 8);
            int g = (f == 0) ? 0 : (L_LEN - f);
            int pf = SW(f), pg = SW(g);
            float ar = re[pf], ai = im[pf];
            float br = re[pg], bi = -im[pg];
            float ur = ar + br, ui = ai + bi;
            float vr = ar - br, vi = ai - bi;
            accR[it] += 0.25f * (ur * vi - ui * vr);
            accI[it] += 0.25f * (ur * vr + ui * vi);
        }
    }
    #pragma unroll
    for (int it = 0; it < 12; it++) {
        int f = tid + (it << 8);
        atomicAdd(&S_re[b * L_LEN + f], accR[it]);
        atomicAdd(&S_im[b * L_LEN + f], accI[it]);
    }
}

// ---------------------------------------------------------------------------
// Fused kernel B+C: inverse FFT of S[b] -> mean_value in LDS -> top-40
// (lowest-index tie-break) -> softmax -> wts[b]; block 0 writes shifts.
// ---------------------------------------------------------------------------
__global__ __launch_bounds__(256) void ifft_topk_kernel(
    const float* __restrict__ S_re, const float* __restrict__ S_im,
    float* __restrict__ wts, int* __restrict__ shifts)
{
    __shared__ float re[FFTSZ], im[FFTSZ];
    __shared__ float Ctab[TWSZ], Stab[TWSZ];
    __shared__ float vals[L_LEN];
    __shared__ float rv[4];
    __shared__ int   ri[4];
    __shared__ float selv[TOPK];
    __shared__ int   seli[TOPK];
    int b = blockIdx.x;
    int tid = threadIdx.x;
    fill_twiddles(Ctab, Stab, tid);
    #pragma unroll
    for (int it = 0; it < 12; it++) {
        int n = tid + (it << 8);
        int m = n / 3;
        int r = n - 3 * m;
        int dst = SW((r << 10) + (__brev((unsigned)m) >> 22));
        re[dst] = S_re[b * L_LEN + n];
        im[dst] = S_im[b * L_LEN + n];
    }
    __syncthreads();
    fft3072(re, im, Ctab, Stab, tid, 1.0f);
    const float scale = 1.0f / (3072.0f * 512.0f);
    #pragma unroll
    for (int it = 0; it < 12; it++) {
        int t = tid + (it << 8);
        vals[t] = re[SW(t)] * scale;
    }
    __syncthreads();

    int wave = tid >> 6;
    int lane = tid & 63;
    for (int kk = 0; kk < TOPK; kk++) {
        float best = -INFINITY;
        int   bi   = 0x7fffffff;
        for (int i = tid; i < L_LEN; i += 256) {
            float vvv = vals[i];
            if (vvv > best || (vvv == best && i < bi)) { best = vvv; bi = i; }
        }
        #pragma unroll
        for (int off = 32; off > 0; off >>= 1) {
            float ov = __shfl_down(best, off);
            int   oi = __shfl_down(bi,  off);
            if (ov > best || (ov == best && oi < bi)) { best = ov; bi = oi; }
        }
        if (lane == 0) { rv[wave] = best; ri[wave] = bi; }
        __syncthreads();
        if (tid == 0) {
            float bv = rv[0]; int bj = ri[0];
            #pragma unroll
            for (int wv = 1; wv < 4; wv++) {
                if (rv[wv] > bv || (rv[wv] == bv && ri[wv] < bj)) { bv = rv[wv]; bj = ri[wv]; }
            }
            selv[kk] = bv; seli[kk] = bj;
            vals[bj] = -INFINITY;
        }
        __syncthreads();
    }
    if (tid == 0) {
        float mx = selv[0];
        float sum = 0.0f;
        float ex[TOPK];
        for (int kk = 0; kk < TOPK; kk++) { ex[kk] = __expf(selv[kk] - mx); sum += ex[kk]; }
        float inv = 1.0f / sum;
        for (int kk = 0; kk < TOPK; kk++) wts[b * TOPK + kk] = ex[kk] * inv;
        if (b == 0)
            for (int kk = 0; kk < TOPK; kk++) shifts[kk] = seli[kk];
    }
}

// ---------------------------------------------------------------------------
// Kernel D: out[b,t,ch] = sum_k w[b,k] * v[b,(t+s_k)%L,ch]
// L2-resident channel-slab tiling: chunk = (b, 64-ch slab) working set
// 3072*256B = 786 KB << 4 MiB XCD L2. blockIdx = slab + 8*(tile + 192*b).
// ---------------------------------------------------------------------------
__global__ __launch_bounds__(256) void agg_kernel(
    const float* __restrict__ v, const float* __restrict__ wts,
    const int* __restrict__ shifts, float* __restrict__ out)
{
    __shared__ float w[TOPK];
    __shared__ int   sh[TOPK];
    int idx  = blockIdx.x;
    int slab = idx & 7;
    int rest = idx >> 3;
    int tile = rest % 192;
    int b    = rest / 192;
    int tid  = threadIdx.x;
    if (tid < TOPK) { w[tid] = wts[b * TOPK + tid]; sh[tid] = shifts[tid]; }
    __syncthreads();
    int t  = (tile << 4) + (tid >> 4);             // 16 rows per block
    int ch = (slab << 6) + ((tid & 15) << 2);      // 64-ch slab, float4 per lane
    size_t vbase = (size_t)b * L_LEN * CH512;
    float4 acc = make_float4(0.0f, 0.0f, 0.0f, 0.0f);
    #pragma unroll 8
    for (int kk = 0; kk < TOPK; kk++) {
        int tt = t + sh[kk];
        if (tt >= L_LEN) tt -= L_LEN;
        const float4 x = *(const float4*)(v + vbase + (size_t)tt * CH512 + ch);
        float ww = w[kk];
        acc.x += x.x * ww; acc.y += x.y * ww;
        acc.z += x.z * ww; acc.w += x.w * ww;
    }
    *(float4*)(out + vbase + (size_t)t * CH512 + ch) = acc;
}

// ---------------------------------------------------------------------------
extern "C" void kernel_launch(void* const* d_in, const int* in_sizes, int n_in,
                              void* d_out, int out_size, void* d_ws, size_t ws_size,
                              hipStream_t stream)
{
    const float* q = (const float*)d_in[0];
    const float* k = (const float*)d_in[1];
    const float* v = (const float*)d_in[2];
    float* out = (float*)d_out;
    float* ws  = (float*)d_ws;

    const size_t TSZ = (size_t)NBATCH * CH512 * L_LEN;   // 12.58M floats

    // qT uses d_out as scratch (agg overwrites it last); kT + small bufs in ws.
    float* qT = out;
    float* kT = ws;
    float* S_re = ws + TSZ;                              // 8*3072
    float* S_im = S_re + NBATCH * L_LEN;                 // 8*3072
    float* wts  = S_im + NBATCH * L_LEN;                 // 8*40
    int*   shifts = (int*)(wts + NBATCH * TOPK);         // 40

    hipMemsetAsync(S_re, 0, (size_t)2 * NBATCH * L_LEN * sizeof(float), stream);

    transpose_kernel<<<dim3(L_LEN / 64, CH512 / 64, NBATCH * 2), dim3(256), 0, stream>>>(
        q, k, qT, kT);
    corr_fft_kernel<<<dim3(512), dim3(256), 0, stream>>>(qT, kT, S_re, S_im);
    ifft_topk_kernel<<<dim3(NBATCH), dim3(256), 0, stream>>>(S_re, S_im, wts, shifts);
    // grid: 8 slabs * 192 t-tiles * 8 batches = 12288 blocks
    agg_kernel<<<dim3(8 * (L_LEN / 16) * NBATCH), dim3(256), 0, stream>>>(v, wts, shifts, out);
}